// Round 6
// baseline (186.857 us; speedup 1.0000x reference)
//
#include <hip/hip_runtime.h>

// SparseNodeConv: out = segment_sum((X@W)[edge_dst] by edge_src) + X@R + bias
// Strategy: AX = segment_sum(X[dst] by src)  (aggregate RAW features, linearity)
//           out = [AX | X](bf16) @ [W; R](bf16) + bias   via MFMA 16x16x32 bf16
//
// Edge grouping by src, coarse-first (NO per-node global atomics):
//  k_chist/k_cscan: coarse (196-bucket) histogram + scan.
//  k_bucket: per-4096-edge-block LDS counting sort -> bucket-contiguous packs.
//  k_fine2 : per-bucket LDS hist+scan -> per-node CSR offs + exact scatter
//            (ushort dst, writes confined to 16KB L2-local window).
//  k_agg   : gather-sum in 4 feature-quarter passes. X is stored QUARTER-MAJOR
//            (4 planes of N x 64B, 3.2MB each): the active plane fits each
//            XCD's 4MB L2, so the random gather hits L2 instead of L3/HBM
//            (round5: 147MB FETCH_SIZE, 59.6us). gridDim.y=plane keeps one
//            plane hot at a time. 8 groups x 8 lanes per wave, uint2 loads.
// N = 50000, E = 1600000, D = 128. Assumes N < 65536 (dst fits 16 bits).

typedef __attribute__((ext_vector_type(8))) short bf16x8;
typedef __attribute__((ext_vector_type(4))) float f32x4;

#define BSH 8  // coarse bucket = 256 nodes

__device__ __forceinline__ unsigned f2bf(float f) {
  unsigned u = __float_as_uint(f);
  return (u + 0x7fffu + ((u >> 16) & 1u)) >> 16;  // RNE
}
__device__ __forceinline__ unsigned pack2(float lo, float hi) {
  return f2bf(lo) | (f2bf(hi) << 16);
}
__device__ __forceinline__ float bflo(unsigned v) { return __uint_as_float(v << 16); }
__device__ __forceinline__ float bfhi(unsigned v) { return __uint_as_float(v & 0xffff0000u); }

// ---------- X (f32) -> Xq (bf16 u32 pairs, QUARTER-MAJOR planes) ----------
// Xq[plane][node][8 uint2]  (plane = 32 cols = 64B per node row)
__global__ __launch_bounds__(256) void k_convert(const float4* __restrict__ X,
                                                 uint2* __restrict__ Xq2,
                                                 int n4, int N_) {
  int stride = gridDim.x * blockDim.x;
  for (int i = blockIdx.x * blockDim.x + threadIdx.x; i < n4; i += stride) {
    float4 v = X[i];
    uint2 o;
    o.x = pack2(v.x, v.y);
    o.y = pack2(v.z, v.w);
    int node = i >> 5;               // 32 float4 per 128-col row
    int plane = (i & 31) >> 3;       // 8 float4 per 32-col quarter
    int w = i & 7;                   // uint2 index within quarter row
    Xq2[(size_t)plane * N_ * 8 + node * 8 + w] = o;
  }
}

// ---------- coarse histogram (K counters) ----------
__global__ __launch_bounds__(256) void k_chist(const int* __restrict__ src,
                                               int* __restrict__ ccnt, int E_, int K_) {
  __shared__ int h[256];
  if (threadIdx.x < K_) h[threadIdx.x] = 0;
  __syncthreads();
  int base = blockIdx.x * 4096;
  int n = min(4096, E_ - base);
  for (int i = threadIdx.x; i < n; i += 256)
    atomicAdd(&h[((unsigned)src[base + i]) >> BSH], 1);
  __syncthreads();
  if (threadIdx.x < K_) {
    int c = h[threadIdx.x];
    if (c > 0) atomicAdd(&ccnt[threadIdx.x], c);
  }
}

// ---------- scan helper ----------
__device__ __forceinline__ int incl_scan256(int v, int tid) {
  int lane = tid & 63, w = tid >> 6;
  int x = v;
#pragma unroll
  for (int d = 1; d < 64; d <<= 1) {
    int o = __shfl_up(x, d, 64);
    if (lane >= d) x += o;
  }
  __shared__ int wsum[4];
  if (lane == 63) wsum[w] = x;
  __syncthreads();
  if (w > 0) x += wsum[0];
  if (w > 1) x += wsum[1];
  if (w > 2) x += wsum[2];
  return x;
}

__global__ __launch_bounds__(256) void k_cscan(const int* __restrict__ ccnt,
                                               int* __restrict__ cbase,
                                               int* __restrict__ cursorC, int K_, int E_) {
  int t = threadIdx.x;
  int v = (t < K_) ? ccnt[t] : 0;
  int incl = incl_scan256(v, t);
  if (t < K_) {
    int e = incl - v;
    cbase[t] = e;
    cursorC[t] = e;
  }
  if (t == 0) cbase[K_] = E_;
}

// ---------- pass A: coarse scatter into 256-node buckets ----------
// pack = (src&255)<<16 | dst   (dst < 65536)
__global__ __launch_bounds__(256) void k_bucket(const int* __restrict__ src,
                                                const int* __restrict__ dst,
                                                int* __restrict__ cursorC,
                                                unsigned* __restrict__ packs,
                                                int E_, int K_) {
  __shared__ int lcnt[256];
  __shared__ int lbase[256];
  __shared__ unsigned lsrc[4096];
  __shared__ unsigned ldst[4096];
  int base = blockIdx.x * 4096;
  int n = min(4096, E_ - base);
  if (threadIdx.x < K_) lcnt[threadIdx.x] = 0;
  __syncthreads();
  for (int i = threadIdx.x; i < n; i += 256) {
    unsigned s = (unsigned)src[base + i];
    unsigned d = (unsigned)dst[base + i];
    lsrc[i] = s;
    ldst[i] = d;
    atomicAdd(&lcnt[s >> BSH], 1);
  }
  __syncthreads();
  if (threadIdx.x < K_) {
    int c = lcnt[threadIdx.x];
    lbase[threadIdx.x] = (c > 0) ? atomicAdd(&cursorC[threadIdx.x], c) : 0;
    lcnt[threadIdx.x] = 0;  // reuse as local cursor
  }
  __syncthreads();
  for (int i = threadIdx.x; i < n; i += 256) {
    unsigned s = lsrc[i], d = ldst[i];
    int b = s >> BSH;
    int r = atomicAdd(&lcnt[b], 1);
    packs[lbase[b] + r] = ((s & 255u) << 16) | d;
  }
}

// ---------- pass B: per-node hist + scan + fine scatter + offs write ----------
__global__ __launch_bounds__(256) void k_fine2(const int* __restrict__ cbase,
                                               const unsigned* __restrict__ packs,
                                               unsigned short* __restrict__ sdst,
                                               int* __restrict__ offs,
                                               int N_, int E_) {
  __shared__ int lcnt[256];
  __shared__ int lbase[256];
  int tid = threadIdx.x;
  int b = blockIdx.x;
  int nodeBase = b << BSH;
  int nNodes = min(256, N_ - nodeBase);
  int beg = cbase[b];
  int n = cbase[b + 1] - beg;  // bucket edge count
  lcnt[tid] = 0;
  __syncthreads();
  for (int i = tid; i < n; i += 256) atomicAdd(&lcnt[packs[beg + i] >> 16], 1);
  __syncthreads();
  int v = lcnt[tid];
  int incl = incl_scan256(v, tid);
  int excl = incl - v;
  lbase[tid] = excl;
  if (tid < nNodes) offs[nodeBase + tid] = beg + excl;
  if (b == gridDim.x - 1 && tid == 0) offs[N_] = E_;
  __syncthreads();
  lcnt[tid] = 0;  // reuse as fine cursor
  __syncthreads();
  for (int i = tid; i < n; i += 256) {
    unsigned p = packs[beg + i];
    int sl = p >> 16;
    int r = atomicAdd(&lcnt[sl], 1);
    sdst[beg + lbase[sl] + r] = (unsigned short)(p & 0xffffu);
  }
}

// ---------- aggregation (per feature-quarter plane) ----------
// wave = 1 node; 8 groups x 8 lanes; lane reads uint2 (4 cols) per edge.
// gridDim.y = plane (0..3): one 3.2MB plane hot in L2 per pass.
__global__ __launch_bounds__(256) void k_agg(const uint2* __restrict__ Xq2,
                                             const int* __restrict__ offs,
                                             const unsigned short* __restrict__ sdst,
                                             uint2* __restrict__ AXq2, int N_) {
  int node = (blockIdx.x * 256 + threadIdx.x) >> 6;
  if (node >= N_) return;
  int lane = threadIdx.x & 63;
  int g = lane >> 3, c = lane & 7;
  const uint2* Xp = Xq2 + (size_t)blockIdx.y * N_ * 8;
  int beg = offs[node], end = offs[node + 1];
  float s0 = 0.f, s1 = 0.f, s2 = 0.f, s3 = 0.f;
  int j = beg + g;
  for (; j + 8 < end; j += 16) {
    int e0 = sdst[j], e1 = sdst[j + 8];
    uint2 v0 = Xp[e0 * 8 + c];
    uint2 v1 = Xp[e1 * 8 + c];
    s0 += bflo(v0.x); s1 += bfhi(v0.x);
    s2 += bflo(v0.y); s3 += bfhi(v0.y);
    s0 += bflo(v1.x); s1 += bfhi(v1.x);
    s2 += bflo(v1.y); s3 += bfhi(v1.y);
  }
  for (; j < end; j += 8) {
    uint2 v = Xp[sdst[j] * 8 + c];
    s0 += bflo(v.x); s1 += bfhi(v.x);
    s2 += bflo(v.y); s3 += bfhi(v.y);
  }
  // reduce across the 8 groups (lane bits 3,4,5)
#pragma unroll
  for (int m = 8; m < 64; m <<= 1) {
    s0 += __shfl_xor(s0, m, 64);
    s1 += __shfl_xor(s1, m, 64);
    s2 += __shfl_xor(s2, m, 64);
    s3 += __shfl_xor(s3, m, 64);
  }
  if (g == 0) {
    uint2 o;
    o.x = pack2(s0, s1);
    o.y = pack2(s2, s3);
    AXq2[(size_t)blockIdx.y * N_ * 8 + node * 8 + c] = o;
  }
}

// ---------- GEMM: out[N,128] = AX@W + X@R + bias (MFMA 16x16x32 bf16) ----------
// A operands read from quarter-major planes: fragment kk == plane kk.
__global__ __launch_bounds__(256) void k_gemm(const unsigned* __restrict__ AXq,
                                              const unsigned* __restrict__ Xq,
                                              const float* __restrict__ Wg,
                                              const float* __restrict__ Rg,
                                              const float* __restrict__ bias,
                                              float* __restrict__ out, int N_) {
  __shared__ __align__(16) unsigned short Bt[128][136];
  int tid = threadIdx.x;
  int wave = tid >> 6, lane = tid & 63;
  int r = lane & 15, g = lane >> 4;
  int rowBase = (blockIdx.x * 4 + wave) * 16;
  int arow = rowBase + r;
  if (arow >= N_) arow = 0;  // clamp; stores are guarded

  bf16x8 fa[4], fx[4];
#pragma unroll
  for (int kk = 0; kk < 4; ++kk) {
    fa[kk] = *(const bf16x8*)(AXq + (size_t)kk * N_ * 16 + (size_t)arow * 16 + g * 4);
    fx[kk] = *(const bf16x8*)(Xq + (size_t)kk * N_ * 16 + (size_t)arow * 16 + g * 4);
  }

  f32x4 acc[8];
#pragma unroll
  for (int n = 0; n < 8; ++n) acc[n] = (f32x4){0.f, 0.f, 0.f, 0.f};

  for (int e = tid; e < 128 * 32; e += 256) {
    int c4 = (e & 31) * 4;
    int k = e >> 5;
    float4 v = *(const float4*)&Wg[k * 128 + c4];
    Bt[c4 + 0][k] = (unsigned short)f2bf(v.x);
    Bt[c4 + 1][k] = (unsigned short)f2bf(v.y);
    Bt[c4 + 2][k] = (unsigned short)f2bf(v.z);
    Bt[c4 + 3][k] = (unsigned short)f2bf(v.w);
  }
  __syncthreads();
#pragma unroll
  for (int n = 0; n < 8; ++n) {
    int col = n * 16 + r;
#pragma unroll
    for (int kk = 0; kk < 4; ++kk) {
      bf16x8 fb = *(const bf16x8*)&Bt[col][kk * 32 + g * 8];
      acc[n] = __builtin_amdgcn_mfma_f32_16x16x32_bf16(fa[kk], fb, acc[n], 0, 0, 0);
    }
  }
  __syncthreads();

  for (int e = tid; e < 128 * 32; e += 256) {
    int c4 = (e & 31) * 4;
    int k = e >> 5;
    float4 v = *(const float4*)&Rg[k * 128 + c4];
    Bt[c4 + 0][k] = (unsigned short)f2bf(v.x);
    Bt[c4 + 1][k] = (unsigned short)f2bf(v.y);
    Bt[c4 + 2][k] = (unsigned short)f2bf(v.z);
    Bt[c4 + 3][k] = (unsigned short)f2bf(v.w);
  }
  __syncthreads();
#pragma unroll
  for (int n = 0; n < 8; ++n) {
    int col = n * 16 + r;
#pragma unroll
    for (int kk = 0; kk < 4; ++kk) {
      bf16x8 fb = *(const bf16x8*)&Bt[col][kk * 32 + g * 8];
      acc[n] = __builtin_amdgcn_mfma_f32_16x16x32_bf16(fx[kk], fb, acc[n], 0, 0, 0);
    }
  }

#pragma unroll
  for (int n = 0; n < 8; ++n) {
    int col = n * 16 + r;
    float bv = bias[col];
#pragma unroll
    for (int jj = 0; jj < 4; ++jj) {
      int row = rowBase + g * 4 + jj;
      if (row < N_) out[(size_t)row * 128 + col] = acc[n][jj] + bv;
    }
  }
}

extern "C" void kernel_launch(void* const* d_in, const int* in_sizes, int n_in,
                              void* d_out, int out_size, void* d_ws, size_t ws_size,
                              hipStream_t stream) {
  const float* X = (const float*)d_in[0];
  const int* esrc = (const int*)d_in[1];
  const int* edst = (const int*)d_in[2];
  const float* Wg = (const float*)d_in[3];
  const float* Rg = (const float*)d_in[4];
  const float* bias = (const float*)d_in[5];
  float* out = (float*)d_out;

  int ND = in_sizes[0];  // N*D
  int E = in_sizes[1];
  int N = ND / 128;
  int K = (N + 255) >> BSH;  // 196 coarse buckets

  char* ws = (char*)d_ws;
  size_t off = 0;
  auto wsalloc = [&](size_t b) {
    char* p = ws + off;
    off = (off + b + 255) & ~(size_t)255;
    return p;
  };
  int* offs = (int*)wsalloc((size_t)(N + 1) * 4);
  unsigned short* sdst = (unsigned short*)wsalloc((size_t)E * 2);
  unsigned* Xq = (unsigned*)wsalloc((size_t)N * 64 * 4);   // 4 planes x N x 16 u32
  unsigned* AXq = (unsigned*)wsalloc((size_t)N * 64 * 4);
  // transient aliases inside the AXq region (dead before k_agg writes AXq):
  unsigned* packs = AXq;                       // E u32 (6.4MB <= 12.8MB)
  int* ccnt = (int*)(AXq + (size_t)E);         // K ints
  int* cbase = ccnt + 512;                     // K+1 ints
  int* cursorC = cbase + 512;                  // K ints

  int nchunk = (E + 4095) / 4096;
  hipMemsetAsync(ccnt, 0, (size_t)K * 4, stream);
  k_convert<<<2048, 256, 0, stream>>>((const float4*)X, (uint2*)Xq, ND / 4, N);
  k_chist<<<nchunk, 256, 0, stream>>>(esrc, ccnt, E, K);
  k_cscan<<<1, 256, 0, stream>>>(ccnt, cbase, cursorC, K, E);
  k_bucket<<<nchunk, 256, 0, stream>>>(esrc, edst, cursorC, packs, E, K);
  k_fine2<<<K, 256, 0, stream>>>(cbase, packs, sdst, offs, N, E);
  dim3 agrid((N + 3) / 4, 4);
  k_agg<<<agrid, 256, 0, stream>>>((const uint2*)Xq, offs, sdst, (uint2*)AXq, N);
  k_gemm<<<(N + 63) / 64, 256, 0, stream>>>(AXq, Xq, Wg, Rg, bias, out, N);
}

// Round 7
// 169.897 us; speedup vs baseline: 1.0998x; 1.0998x over previous
//
#include <hip/hip_runtime.h>

// SparseNodeConv: out = segment_sum((X@W)[edge_dst] by edge_src) + X@R + bias
// Strategy: AX = segment_sum(X[dst] by src)  (aggregate RAW features, linearity)
//           out = [AX | X](bf16) @ [W; R](bf16) + bias   via MFMA 16x16x32 bf16
//
// Edge grouping by src, coarse-first (NO per-node global atomics):
//  k_chist/k_cscan: coarse (196-bucket) histogram + scan.
//  k_bucket: per-4096-edge-block LDS counting sort -> bucket-contiguous packs.
//  k_fine2 : per-bucket LDS hist+scan -> per-node CSR offs + exact scatter
//            (ushort dst, writes confined to 16KB L2-local window).
//  k_agg   : gather-sum, ROW-MAJOR Xb (round-6's 4-plane split regressed:
//            latency/instruction-bound at 47% VALU; full-row wave gather at
//            2.73 TB/s effective L3 BW is the better regime). One wave = one
//            node, lane = one u32 (2 cols), 8-deep edge unroll for MLP.
// N = 50000, E = 1600000, D = 128. Assumes N < 65536 (dst fits 16 bits).

typedef __attribute__((ext_vector_type(8))) short bf16x8;
typedef __attribute__((ext_vector_type(4))) float f32x4;

#define BSH 8  // coarse bucket = 256 nodes

__device__ __forceinline__ unsigned f2bf(float f) {
  unsigned u = __float_as_uint(f);
  return (u + 0x7fffu + ((u >> 16) & 1u)) >> 16;  // RNE
}
__device__ __forceinline__ unsigned pack2(float lo, float hi) {
  return f2bf(lo) | (f2bf(hi) << 16);
}
__device__ __forceinline__ float bflo(unsigned v) { return __uint_as_float(v << 16); }
__device__ __forceinline__ float bfhi(unsigned v) { return __uint_as_float(v & 0xffff0000u); }

// ---------- X (f32) -> Xb (bf16 packed u32 pairs, row-major) ----------
__global__ __launch_bounds__(256) void k_convert(const float4* __restrict__ X,
                                                 uint2* __restrict__ Xb, int n4) {
  int stride = gridDim.x * blockDim.x;
  for (int i = blockIdx.x * blockDim.x + threadIdx.x; i < n4; i += stride) {
    float4 v = X[i];
    uint2 o;
    o.x = pack2(v.x, v.y);
    o.y = pack2(v.z, v.w);
    Xb[i] = o;
  }
}

// ---------- coarse histogram (K counters) ----------
__global__ __launch_bounds__(256) void k_chist(const int* __restrict__ src,
                                               int* __restrict__ ccnt, int E_, int K_) {
  __shared__ int h[256];
  if (threadIdx.x < K_) h[threadIdx.x] = 0;
  __syncthreads();
  int base = blockIdx.x * 4096;
  int n = min(4096, E_ - base);
  for (int i = threadIdx.x; i < n; i += 256)
    atomicAdd(&h[((unsigned)src[base + i]) >> BSH], 1);
  __syncthreads();
  if (threadIdx.x < K_) {
    int c = h[threadIdx.x];
    if (c > 0) atomicAdd(&ccnt[threadIdx.x], c);
  }
}

// ---------- scan helper ----------
__device__ __forceinline__ int incl_scan256(int v, int tid) {
  int lane = tid & 63, w = tid >> 6;
  int x = v;
#pragma unroll
  for (int d = 1; d < 64; d <<= 1) {
    int o = __shfl_up(x, d, 64);
    if (lane >= d) x += o;
  }
  __shared__ int wsum[4];
  if (lane == 63) wsum[w] = x;
  __syncthreads();
  if (w > 0) x += wsum[0];
  if (w > 1) x += wsum[1];
  if (w > 2) x += wsum[2];
  return x;
}

__global__ __launch_bounds__(256) void k_cscan(const int* __restrict__ ccnt,
                                               int* __restrict__ cbase,
                                               int* __restrict__ cursorC, int K_, int E_) {
  int t = threadIdx.x;
  int v = (t < K_) ? ccnt[t] : 0;
  int incl = incl_scan256(v, t);
  if (t < K_) {
    int e = incl - v;
    cbase[t] = e;
    cursorC[t] = e;
  }
  if (t == 0) cbase[K_] = E_;
}

// ---------- pass A: coarse scatter into 256-node buckets ----------
// pack = (src&255)<<16 | dst   (dst < 65536)
__global__ __launch_bounds__(256) void k_bucket(const int* __restrict__ src,
                                                const int* __restrict__ dst,
                                                int* __restrict__ cursorC,
                                                unsigned* __restrict__ packs,
                                                int E_, int K_) {
  __shared__ int lcnt[256];
  __shared__ int lbase[256];
  __shared__ unsigned lsrc[4096];
  __shared__ unsigned ldst[4096];
  int base = blockIdx.x * 4096;
  int n = min(4096, E_ - base);
  if (threadIdx.x < K_) lcnt[threadIdx.x] = 0;
  __syncthreads();
  for (int i = threadIdx.x; i < n; i += 256) {
    unsigned s = (unsigned)src[base + i];
    unsigned d = (unsigned)dst[base + i];
    lsrc[i] = s;
    ldst[i] = d;
    atomicAdd(&lcnt[s >> BSH], 1);
  }
  __syncthreads();
  if (threadIdx.x < K_) {
    int c = lcnt[threadIdx.x];
    lbase[threadIdx.x] = (c > 0) ? atomicAdd(&cursorC[threadIdx.x], c) : 0;
    lcnt[threadIdx.x] = 0;  // reuse as local cursor
  }
  __syncthreads();
  for (int i = threadIdx.x; i < n; i += 256) {
    unsigned s = lsrc[i], d = ldst[i];
    int b = s >> BSH;
    int r = atomicAdd(&lcnt[b], 1);
    packs[lbase[b] + r] = ((s & 255u) << 16) | d;
  }
}

// ---------- pass B: per-node hist + scan + fine scatter + offs write ----------
__global__ __launch_bounds__(256) void k_fine2(const int* __restrict__ cbase,
                                               const unsigned* __restrict__ packs,
                                               unsigned short* __restrict__ sdst,
                                               int* __restrict__ offs,
                                               int N_, int E_) {
  __shared__ int lcnt[256];
  __shared__ int lbase[256];
  int tid = threadIdx.x;
  int b = blockIdx.x;
  int nodeBase = b << BSH;
  int nNodes = min(256, N_ - nodeBase);
  int beg = cbase[b];
  int n = cbase[b + 1] - beg;  // bucket edge count
  lcnt[tid] = 0;
  __syncthreads();
  for (int i = tid; i < n; i += 256) atomicAdd(&lcnt[packs[beg + i] >> 16], 1);
  __syncthreads();
  int v = lcnt[tid];
  int incl = incl_scan256(v, tid);
  int excl = incl - v;
  lbase[tid] = excl;
  if (tid < nNodes) offs[nodeBase + tid] = beg + excl;
  if (b == gridDim.x - 1 && tid == 0) offs[N_] = E_;
  __syncthreads();
  lcnt[tid] = 0;  // reuse as fine cursor
  __syncthreads();
  for (int i = tid; i < n; i += 256) {
    unsigned p = packs[beg + i];
    int sl = p >> 16;
    int r = atomicAdd(&lcnt[sl], 1);
    sdst[beg + lbase[sl] + r] = (unsigned short)(p & 0xffffu);
  }
}

// ---------- aggregation: AXb[i] = sum over CSR segment i of Xb[dst] ----------
// one wave per node; lane owns one u32 (2 bf16 cols); fp32 accumulate;
// 8-deep edge unroll to keep 8 gathers in flight per lane.
__global__ __launch_bounds__(1024, 8) void k_agg(const unsigned* __restrict__ Xb,
                                                 const int* __restrict__ offs,
                                                 const unsigned short* __restrict__ sdst,
                                                 unsigned* __restrict__ AXb, int N_) {
  int wid = (blockIdx.x * 1024 + threadIdx.x) >> 6;
  int lane = threadIdx.x & 63;
  if (wid >= N_) return;
  int j = offs[wid], end = offs[wid + 1];
  float a0 = 0.f, a1 = 0.f;
  for (; j + 8 <= end; j += 8) {
    unsigned e0 = sdst[j + 0], e1 = sdst[j + 1], e2 = sdst[j + 2], e3 = sdst[j + 3];
    unsigned e4 = sdst[j + 4], e5 = sdst[j + 5], e6 = sdst[j + 6], e7 = sdst[j + 7];
    unsigned v0 = Xb[(size_t)e0 * 64 + lane];
    unsigned v1 = Xb[(size_t)e1 * 64 + lane];
    unsigned v2 = Xb[(size_t)e2 * 64 + lane];
    unsigned v3 = Xb[(size_t)e3 * 64 + lane];
    unsigned v4 = Xb[(size_t)e4 * 64 + lane];
    unsigned v5 = Xb[(size_t)e5 * 64 + lane];
    unsigned v6 = Xb[(size_t)e6 * 64 + lane];
    unsigned v7 = Xb[(size_t)e7 * 64 + lane];
    a0 += bflo(v0); a1 += bfhi(v0);
    a0 += bflo(v1); a1 += bfhi(v1);
    a0 += bflo(v2); a1 += bfhi(v2);
    a0 += bflo(v3); a1 += bfhi(v3);
    a0 += bflo(v4); a1 += bfhi(v4);
    a0 += bflo(v5); a1 += bfhi(v5);
    a0 += bflo(v6); a1 += bfhi(v6);
    a0 += bflo(v7); a1 += bfhi(v7);
  }
  for (; j < end; ++j) {
    unsigned v = Xb[(size_t)sdst[j] * 64 + lane];
    a0 += bflo(v); a1 += bfhi(v);
  }
  AXb[(size_t)wid * 64 + lane] = pack2(a0, a1);
}

// ---------- GEMM: out[N,128] = AXb@W + Xb@R + bias (MFMA 16x16x32 bf16) ----------
__global__ __launch_bounds__(256) void k_gemm(const unsigned* __restrict__ AXb,
                                              const unsigned* __restrict__ Xb,
                                              const float* __restrict__ Wg,
                                              const float* __restrict__ Rg,
                                              const float* __restrict__ bias,
                                              float* __restrict__ out, int N_) {
  __shared__ __align__(16) unsigned short Bt[128][136];
  int tid = threadIdx.x;
  int wave = tid >> 6, lane = tid & 63;
  int r = lane & 15, g = lane >> 4;
  int rowBase = (blockIdx.x * 4 + wave) * 16;
  int arow = rowBase + r;
  if (arow >= N_) arow = 0;  // clamp; stores are guarded

  bf16x8 fa[4], fx[4];
  const bf16x8* pA = (const bf16x8*)(AXb + (size_t)arow * 64);
  const bf16x8* pX = (const bf16x8*)(Xb + (size_t)arow * 64);
#pragma unroll
  for (int kk = 0; kk < 4; ++kk) {
    fa[kk] = pA[kk * 4 + g];
    fx[kk] = pX[kk * 4 + g];
  }

  f32x4 acc[8];
#pragma unroll
  for (int n = 0; n < 8; ++n) acc[n] = (f32x4){0.f, 0.f, 0.f, 0.f};

  for (int e = tid; e < 128 * 32; e += 256) {
    int c4 = (e & 31) * 4;
    int k = e >> 5;
    float4 v = *(const float4*)&Wg[k * 128 + c4];
    Bt[c4 + 0][k] = (unsigned short)f2bf(v.x);
    Bt[c4 + 1][k] = (unsigned short)f2bf(v.y);
    Bt[c4 + 2][k] = (unsigned short)f2bf(v.z);
    Bt[c4 + 3][k] = (unsigned short)f2bf(v.w);
  }
  __syncthreads();
#pragma unroll
  for (int n = 0; n < 8; ++n) {
    int col = n * 16 + r;
#pragma unroll
    for (int kk = 0; kk < 4; ++kk) {
      bf16x8 fb = *(const bf16x8*)&Bt[col][kk * 32 + g * 8];
      acc[n] = __builtin_amdgcn_mfma_f32_16x16x32_bf16(fa[kk], fb, acc[n], 0, 0, 0);
    }
  }
  __syncthreads();

  for (int e = tid; e < 128 * 32; e += 256) {
    int c4 = (e & 31) * 4;
    int k = e >> 5;
    float4 v = *(const float4*)&Rg[k * 128 + c4];
    Bt[c4 + 0][k] = (unsigned short)f2bf(v.x);
    Bt[c4 + 1][k] = (unsigned short)f2bf(v.y);
    Bt[c4 + 2][k] = (unsigned short)f2bf(v.z);
    Bt[c4 + 3][k] = (unsigned short)f2bf(v.w);
  }
  __syncthreads();
#pragma unroll
  for (int n = 0; n < 8; ++n) {
    int col = n * 16 + r;
#pragma unroll
    for (int kk = 0; kk < 4; ++kk) {
      bf16x8 fb = *(const bf16x8*)&Bt[col][kk * 32 + g * 8];
      acc[n] = __builtin_amdgcn_mfma_f32_16x16x32_bf16(fx[kk], fb, acc[n], 0, 0, 0);
    }
  }

#pragma unroll
  for (int n = 0; n < 8; ++n) {
    int col = n * 16 + r;
    float bv = bias[col];
#pragma unroll
    for (int jj = 0; jj < 4; ++jj) {
      int row = rowBase + g * 4 + jj;
      if (row < N_) out[(size_t)row * 128 + col] = acc[n][jj] + bv;
    }
  }
}

extern "C" void kernel_launch(void* const* d_in, const int* in_sizes, int n_in,
                              void* d_out, int out_size, void* d_ws, size_t ws_size,
                              hipStream_t stream) {
  const float* X = (const float*)d_in[0];
  const int* esrc = (const int*)d_in[1];
  const int* edst = (const int*)d_in[2];
  const float* Wg = (const float*)d_in[3];
  const float* Rg = (const float*)d_in[4];
  const float* bias = (const float*)d_in[5];
  float* out = (float*)d_out;

  int ND = in_sizes[0];  // N*D
  int E = in_sizes[1];
  int N = ND / 128;
  int K = (N + 255) >> BSH;  // 196 coarse buckets

  char* ws = (char*)d_ws;
  size_t off = 0;
  auto wsalloc = [&](size_t b) {
    char* p = ws + off;
    off = (off + b + 255) & ~(size_t)255;
    return p;
  };
  int* offs = (int*)wsalloc((size_t)(N + 1) * 4);
  unsigned short* sdst = (unsigned short*)wsalloc((size_t)E * 2);
  unsigned* Xb = (unsigned*)wsalloc((size_t)N * 64 * 4);
  unsigned* AXb = (unsigned*)wsalloc((size_t)N * 64 * 4);
  // transient aliases inside the AXb region (dead before k_agg writes AXb):
  unsigned* packs = AXb;                       // E u32 (6.4MB <= 12.8MB)
  int* ccnt = (int*)(AXb + (size_t)E);         // K ints
  int* cbase = ccnt + 512;                     // K+1 ints
  int* cursorC = cbase + 512;                  // K ints

  int nchunk = (E + 4095) / 4096;
  hipMemsetAsync(ccnt, 0, (size_t)K * 4, stream);
  k_convert<<<2048, 256, 0, stream>>>((const float4*)X, (uint2*)Xb, ND / 4);
  k_chist<<<nchunk, 256, 0, stream>>>(esrc, ccnt, E, K);
  k_cscan<<<1, 256, 0, stream>>>(ccnt, cbase, cursorC, K, E);
  k_bucket<<<nchunk, 256, 0, stream>>>(esrc, edst, cursorC, packs, E, K);
  k_fine2<<<K, 256, 0, stream>>>(cbase, packs, sdst, offs, N, E);
  k_agg<<<(N + 15) / 16, 1024, 0, stream>>>(Xb, offs, sdst, AXb, N);
  k_gemm<<<(N + 63) / 64, 256, 0, stream>>>(AXb, Xb, Wg, Rg, bias, out, N);
}

// Round 8
// 158.809 us; speedup vs baseline: 1.1766x; 1.0698x over previous
//
#include <hip/hip_runtime.h>

// SparseNodeConv: out = segment_sum((X@W)[edge_dst] by edge_src) + X@R + bias
// Strategy: AX = segment_sum(X[dst] by src)  (aggregate RAW features, linearity)
//           out = [AX | X](bf16) @ [W; R](bf16) + bias   via MFMA 16x16x32 bf16
//
// Pipeline (6 dispatches incl. memset):
//  k_convhist: X f32 -> Xb bf16 (row-major)  +  coarse 196-bucket histogram.
//  k_bucket  : per-block inline scan of ccnt -> cbase; per-4096-edge LDS
//              counting sort -> bucket-contiguous packs (atomic reservation
//              on zero-initialized cursor0).
//  k_fine    : per-bucket inline scan -> beg; LDS per-node hist+scan ->
//              per-node CSR offs + exact scatter (ushort dst).
//  k_agg     : gather-sum. lane quarter q handles edge j+q, 16 lanes x 16B
//              cover one 256B row -> 4 edges per VMEM instr (round7 was 2
//              instr/edge and time-invariant vs unroll/occupancy; testing
//              instruction-rate vs L3-random-BW bound). Cross-quarter
//              reduce = 16 shfl_xor per NODE (not per edge; round6's
//              per-edge-shuffle structure regressed).
//  k_gemm    : [AX|X] @ [W;R] + bias, MFMA 16x16x32 bf16.
// N = 50000, E = 1600000, D = 128. Assumes N < 65536 (dst fits 16 bits).

typedef __attribute__((ext_vector_type(8))) short bf16x8;
typedef __attribute__((ext_vector_type(4))) float f32x4;

#define BSH 8  // coarse bucket = 256 nodes

__device__ __forceinline__ unsigned f2bf(float f) {
  unsigned u = __float_as_uint(f);
  return (u + 0x7fffu + ((u >> 16) & 1u)) >> 16;  // RNE
}
__device__ __forceinline__ unsigned pack2(float lo, float hi) {
  return f2bf(lo) | (f2bf(hi) << 16);
}
__device__ __forceinline__ float bflo(unsigned v) { return __uint_as_float(v << 16); }
__device__ __forceinline__ float bfhi(unsigned v) { return __uint_as_float(v & 0xffff0000u); }

// ---------- fused: X (f32) -> Xb (bf16 u32 pairs) + coarse histogram ----------
__global__ __launch_bounds__(256) void k_convhist(const float4* __restrict__ X,
                                                  uint2* __restrict__ Xb, int n4,
                                                  const int* __restrict__ src,
                                                  int* __restrict__ ccnt,
                                                  int E_, int K_) {
  __shared__ int h[256];
  if (threadIdx.x < K_) h[threadIdx.x] = 0;
  int stride = gridDim.x * blockDim.x;
  int gtid = blockIdx.x * blockDim.x + threadIdx.x;
  for (int i = gtid; i < n4; i += stride) {
    float4 v = X[i];
    uint2 o;
    o.x = pack2(v.x, v.y);
    o.y = pack2(v.z, v.w);
    Xb[i] = o;
  }
  __syncthreads();
  for (int i = gtid; i < E_; i += stride)
    atomicAdd(&h[((unsigned)src[i]) >> BSH], 1);
  __syncthreads();
  if (threadIdx.x < K_) {
    int c = h[threadIdx.x];
    if (c > 0) atomicAdd(&ccnt[threadIdx.x], c);
  }
}

// ---------- scan helper (256 threads, has __syncthreads) ----------
__device__ __forceinline__ int incl_scan256(int v, int tid) {
  int lane = tid & 63, w = tid >> 6;
  int x = v;
#pragma unroll
  for (int d = 1; d < 64; d <<= 1) {
    int o = __shfl_up(x, d, 64);
    if (lane >= d) x += o;
  }
  __shared__ int wsum[4];
  if (lane == 63) wsum[w] = x;
  __syncthreads();
  if (w > 0) x += wsum[0];
  if (w > 1) x += wsum[1];
  if (w > 2) x += wsum[2];
  return x;
}

// ---------- pass A: coarse scatter into 256-node buckets ----------
// inline scan of ccnt -> cbaseL; reservation via cursor0 (zeroed).
// pack = (src&255)<<16 | dst   (dst < 65536)
__global__ __launch_bounds__(256) void k_bucket(const int* __restrict__ src,
                                                const int* __restrict__ dst,
                                                const int* __restrict__ ccnt,
                                                int* __restrict__ cursor0,
                                                unsigned* __restrict__ packs,
                                                int E_, int K_) {
  __shared__ int lcnt[256];
  __shared__ int lbase[256];
  __shared__ unsigned lsrc[4096];
  __shared__ unsigned ldst[4096];
  int tid = threadIdx.x;
  // local exclusive scan of coarse counts -> absolute bucket bases
  int cv = (tid < K_) ? ccnt[tid] : 0;
  int cincl = incl_scan256(cv, tid);
  int cbaseL = cincl - cv;
  lcnt[tid] = 0;
  __syncthreads();
  int base = blockIdx.x * 4096;
  int n = min(4096, E_ - base);
  for (int i = tid; i < n; i += 256) {
    unsigned s = (unsigned)src[base + i];
    unsigned d = (unsigned)dst[base + i];
    lsrc[i] = s;
    ldst[i] = d;
    atomicAdd(&lcnt[s >> BSH], 1);
  }
  __syncthreads();
  if (tid < K_) {
    int c = lcnt[tid];
    int r = (c > 0) ? atomicAdd(&cursor0[tid], c) : 0;
    lbase[tid] = cbaseL + r;
    lcnt[tid] = 0;  // reuse as local rank cursor
  }
  __syncthreads();
  for (int i = tid; i < n; i += 256) {
    unsigned s = lsrc[i], d = ldst[i];
    int b = s >> BSH;
    int r = atomicAdd(&lcnt[b], 1);
    packs[lbase[b] + r] = ((s & 255u) << 16) | d;
  }
}

// ---------- pass B: per-node hist + scan + fine scatter + offs write ----------
__global__ __launch_bounds__(256) void k_fine(const int* __restrict__ ccnt,
                                              const unsigned* __restrict__ packs,
                                              unsigned short* __restrict__ sdst,
                                              int* __restrict__ offs,
                                              int N_, int E_, int K_) {
  __shared__ int lcnt[256];
  __shared__ int lbase[256];
  int tid = threadIdx.x;
  int b = blockIdx.x;
  // local scan of coarse counts -> this bucket's [beg, beg+n)
  int cv = (tid < K_) ? ccnt[tid] : 0;
  int cincl = incl_scan256(cv, tid);
  __shared__ int sh_beg, sh_n;
  if (tid == b) {
    sh_beg = cincl - cv;
    sh_n = cv;
  }
  lcnt[tid] = 0;
  __syncthreads();
  int beg = sh_beg;
  int n = sh_n;
  int nodeBase = b << BSH;
  int nNodes = min(256, N_ - nodeBase);
  // per-node histogram of this bucket (LDS atomics)
  for (int i = tid; i < n; i += 256) atomicAdd(&lcnt[packs[beg + i] >> 16], 1);
  __syncthreads();
  int v = lcnt[tid];
  int incl = incl_scan256(v, tid);
  int excl = incl - v;
  lbase[tid] = excl;
  if (tid < nNodes) offs[nodeBase + tid] = beg + excl;
  if (b == gridDim.x - 1 && tid == 0) offs[N_] = E_;
  __syncthreads();
  lcnt[tid] = 0;  // reuse as fine cursor
  __syncthreads();
  for (int i = tid; i < n; i += 256) {
    unsigned p = packs[beg + i];
    int sl = p >> 16;
    int r = atomicAdd(&lcnt[sl], 1);
    sdst[beg + lbase[sl] + r] = (unsigned short)(p & 0xffffu);
  }
}

// ---------- aggregation: AXb[i] = sum over CSR segment i of Xb[dst] ----------
// one wave = one node; quarter q = edge j+q; 16 lanes x uint4 = one 256B row.
__global__ __launch_bounds__(256) void k_agg(const uint4* __restrict__ Xb4,
                                             const int* __restrict__ offs,
                                             const unsigned short* __restrict__ sdst,
                                             uint4* __restrict__ AXb4, int N_) {
  int node = (blockIdx.x * 256 + threadIdx.x) >> 6;
  if (node >= N_) return;
  int lane = threadIdx.x & 63;
  int q = lane >> 4, c = lane & 15;
  int beg = offs[node], end = offs[node + 1];
  float a0 = 0.f, a1 = 0.f, a2 = 0.f, a3 = 0.f;
  float a4 = 0.f, a5 = 0.f, a6 = 0.f, a7 = 0.f;
  int j = beg;
#pragma unroll 2
  for (; j + 4 <= end; j += 4) {
    int e = sdst[j + q];
    uint4 v = Xb4[(size_t)e * 16 + c];
    a0 += bflo(v.x); a1 += bfhi(v.x);
    a2 += bflo(v.y); a3 += bfhi(v.y);
    a4 += bflo(v.z); a5 += bfhi(v.z);
    a6 += bflo(v.w); a7 += bfhi(v.w);
  }
  if (j + q < end) {  // tail (16-lane-group-uniform predicate)
    int e = sdst[j + q];
    uint4 v = Xb4[(size_t)e * 16 + c];
    a0 += bflo(v.x); a1 += bfhi(v.x);
    a2 += bflo(v.y); a3 += bfhi(v.y);
    a4 += bflo(v.z); a5 += bfhi(v.z);
    a6 += bflo(v.w); a7 += bfhi(v.w);
  }
  // cross-quarter reduce (once per node)
  a0 += __shfl_xor(a0, 16, 64); a1 += __shfl_xor(a1, 16, 64);
  a2 += __shfl_xor(a2, 16, 64); a3 += __shfl_xor(a3, 16, 64);
  a4 += __shfl_xor(a4, 16, 64); a5 += __shfl_xor(a5, 16, 64);
  a6 += __shfl_xor(a6, 16, 64); a7 += __shfl_xor(a7, 16, 64);
  a0 += __shfl_xor(a0, 32, 64); a1 += __shfl_xor(a1, 32, 64);
  a2 += __shfl_xor(a2, 32, 64); a3 += __shfl_xor(a3, 32, 64);
  a4 += __shfl_xor(a4, 32, 64); a5 += __shfl_xor(a5, 32, 64);
  a6 += __shfl_xor(a6, 32, 64); a7 += __shfl_xor(a7, 32, 64);
  if (q == 0) {
    uint4 o;
    o.x = pack2(a0, a1);
    o.y = pack2(a2, a3);
    o.z = pack2(a4, a5);
    o.w = pack2(a6, a7);
    AXb4[(size_t)node * 16 + c] = o;
  }
}

// ---------- GEMM: out[N,128] = AXb@W + Xb@R + bias (MFMA 16x16x32 bf16) ----------
__global__ __launch_bounds__(256) void k_gemm(const unsigned* __restrict__ AXb,
                                              const unsigned* __restrict__ Xb,
                                              const float* __restrict__ Wg,
                                              const float* __restrict__ Rg,
                                              const float* __restrict__ bias,
                                              float* __restrict__ out, int N_) {
  __shared__ __align__(16) unsigned short Bt[128][136];
  int tid = threadIdx.x;
  int wave = tid >> 6, lane = tid & 63;
  int r = lane & 15, g = lane >> 4;
  int rowBase = (blockIdx.x * 4 + wave) * 16;
  int arow = rowBase + r;
  if (arow >= N_) arow = 0;  // clamp; stores are guarded

  bf16x8 fa[4], fx[4];
  const bf16x8* pA = (const bf16x8*)(AXb + (size_t)arow * 64);
  const bf16x8* pX = (const bf16x8*)(Xb + (size_t)arow * 64);
#pragma unroll
  for (int kk = 0; kk < 4; ++kk) {
    fa[kk] = pA[kk * 4 + g];
    fx[kk] = pX[kk * 4 + g];
  }

  f32x4 acc[8];
#pragma unroll
  for (int n = 0; n < 8; ++n) acc[n] = (f32x4){0.f, 0.f, 0.f, 0.f};

  for (int e = tid; e < 128 * 32; e += 256) {
    int c4 = (e & 31) * 4;
    int k = e >> 5;
    float4 v = *(const float4*)&Wg[k * 128 + c4];
    Bt[c4 + 0][k] = (unsigned short)f2bf(v.x);
    Bt[c4 + 1][k] = (unsigned short)f2bf(v.y);
    Bt[c4 + 2][k] = (unsigned short)f2bf(v.z);
    Bt[c4 + 3][k] = (unsigned short)f2bf(v.w);
  }
  __syncthreads();
#pragma unroll
  for (int n = 0; n < 8; ++n) {
    int col = n * 16 + r;
#pragma unroll
    for (int kk = 0; kk < 4; ++kk) {
      bf16x8 fb = *(const bf16x8*)&Bt[col][kk * 32 + g * 8];
      acc[n] = __builtin_amdgcn_mfma_f32_16x16x32_bf16(fa[kk], fb, acc[n], 0, 0, 0);
    }
  }
  __syncthreads();

  for (int e = tid; e < 128 * 32; e += 256) {
    int c4 = (e & 31) * 4;
    int k = e >> 5;
    float4 v = *(const float4*)&Rg[k * 128 + c4];
    Bt[c4 + 0][k] = (unsigned short)f2bf(v.x);
    Bt[c4 + 1][k] = (unsigned short)f2bf(v.y);
    Bt[c4 + 2][k] = (unsigned short)f2bf(v.z);
    Bt[c4 + 3][k] = (unsigned short)f2bf(v.w);
  }
  __syncthreads();
#pragma unroll
  for (int n = 0; n < 8; ++n) {
    int col = n * 16 + r;
#pragma unroll
    for (int kk = 0; kk < 4; ++kk) {
      bf16x8 fb = *(const bf16x8*)&Bt[col][kk * 32 + g * 8];
      acc[n] = __builtin_amdgcn_mfma_f32_16x16x32_bf16(fx[kk], fb, acc[n], 0, 0, 0);
    }
  }

#pragma unroll
  for (int n = 0; n < 8; ++n) {
    int col = n * 16 + r;
    float bv = bias[col];
#pragma unroll
    for (int jj = 0; jj < 4; ++jj) {
      int row = rowBase + g * 4 + jj;
      if (row < N_) out[(size_t)row * 128 + col] = acc[n][jj] + bv;
    }
  }
}

extern "C" void kernel_launch(void* const* d_in, const int* in_sizes, int n_in,
                              void* d_out, int out_size, void* d_ws, size_t ws_size,
                              hipStream_t stream) {
  const float* X = (const float*)d_in[0];
  const int* esrc = (const int*)d_in[1];
  const int* edst = (const int*)d_in[2];
  const float* Wg = (const float*)d_in[3];
  const float* Rg = (const float*)d_in[4];
  const float* bias = (const float*)d_in[5];
  float* out = (float*)d_out;

  int ND = in_sizes[0];  // N*D
  int E = in_sizes[1];
  int N = ND / 128;
  int K = (N + 255) >> BSH;  // 196 coarse buckets

  char* ws = (char*)d_ws;
  size_t off = 0;
  auto wsalloc = [&](size_t b) {
    char* p = ws + off;
    off = (off + b + 255) & ~(size_t)255;
    return p;
  };
  int* offs = (int*)wsalloc((size_t)(N + 1) * 4);
  unsigned short* sdst = (unsigned short*)wsalloc((size_t)E * 2);
  unsigned* Xb = (unsigned*)wsalloc((size_t)N * 64 * 4);
  unsigned* AXb = (unsigned*)wsalloc((size_t)N * 64 * 4);
  // transient aliases inside the AXb region (dead before k_agg writes AXb):
  unsigned* packs = AXb;                       // E u32 (6.4MB <= 12.8MB)
  int* ccnt = (int*)(AXb + (size_t)E);         // 512 ints (K used)
  int* cursor0 = ccnt + 512;                   // 512 ints (K used)

  int nchunk = (E + 4095) / 4096;
  hipMemsetAsync(ccnt, 0, 1024 * 4, stream);  // ccnt + cursor0
  k_convhist<<<512, 256, 0, stream>>>((const float4*)X, (uint2*)Xb, ND / 4,
                                      esrc, ccnt, E, K);
  k_bucket<<<nchunk, 256, 0, stream>>>(esrc, edst, ccnt, cursor0, packs, E, K);
  k_fine<<<K, 256, 0, stream>>>(ccnt, packs, sdst, offs, N, E, K);
  k_agg<<<(N + 3) / 4, 256, 0, stream>>>((const uint4*)Xb, offs, sdst,
                                         (uint4*)AXb, N);
  k_gemm<<<(N + 63) / 64, 256, 0, stream>>>(AXb, Xb, Wg, Rg, bias, out, N);
}